// Round 1
// baseline (132.082 us; speedup 1.0000x reference)
//
#include <hip/hip_runtime.h>
#include <hip/hip_bf16.h>

// Flash-style masked dot-product attention. fp32 I/O, bf16 MFMA compute.
// n=32, s=2048, d=64. R8 vs R7 (46us attn rocprof): DS-pipe-bound
// (66 block-tiles/CU x ~1250 DS cyc + 24K conflict cyc ~= the full 110K cyc).
// Changes:
//  1) 32x32x16 MFMA, waves = 2 q-groups (32q) x 2 key-parity groups ->
//     each wave reads K/V tile exactly once (8+8 b128 = info minimum);
//     DS per 64q-tile: 104 -> 48 wave-instrs.
//  2) P exchange fully in-register via v_permlane32_swap_b32 (2 per K=16
//     step): S^T C-layout (m74/m101: col=q=l31, row=(r&3)+8*(r>>2)+4*hi)
//     means dest A-frag words = {own pk[4t],pk[4t+1] | partner pk[4t+2],
//     pk[4t+3]} across the hi halves == exactly the swap semantics.
//     No P LDS roundtrip, no fence.
//  3) key-parity pairs stage/compute alternate kt concurrently: barriers
//     per tile halved, worst-case serial depth 32 -> 16 tiles. Epilogue
//     combines the two partial (O,l) via one-time LDS reduction.
// Kept: prepass (K->bf16, V->bf16 transposed in ws), LPT snake, fixed-max
// softmax p=exp2(S) with Q pre-scaled by 0.125*log2e, row-sums via ones-MFMA.
// 32x32x16 bf16 layouts: A[m=l31][k=(l>>5)*8+j]  B[k=(l>>5)*8+j][n=l31]
//   C/D: col=l31, row=(r&3)+8*(r>>2)+4*(l>>5).

typedef short bf16x8 __attribute__((ext_vector_type(8)));
typedef float f32x4  __attribute__((ext_vector_type(4)));
typedef float f32x16 __attribute__((ext_vector_type(16)));
typedef unsigned int u32;
typedef u32 u32x2 __attribute__((ext_vector_type(2)));
typedef u32 u32x4 __attribute__((ext_vector_type(4)));

#define SEQ 2048
#define DH 64
#define BK 64
#define LDSP 72   // 144B rows: 16B-aligned, 32-row b128 reads spread evenly
#define SCLQ 0.18033688011112042f   // (1/sqrt(64)) * log2(e)

static __device__ __forceinline__ short f2bf(float f) {
    unsigned u = __float_as_uint(f);
    return (short)((u + 0x7FFFu + ((u >> 16) & 1u)) >> 16);   // RNE, finite
}
static __device__ __forceinline__ u32 pk2bf(float lo, float hi) {
    __hip_bfloat162 h = __float22bfloat162_rn(float2{lo, hi});  // v_cvt_pk_bf16_f32
    return *(u32*)&h;
}
// exchanges: a[l>=32] <- b[l-32] ; b[l<32] <- a[l+32]
static __device__ __forceinline__ void pl32swap(u32& a, u32& b) {
    asm volatile("v_permlane32_swap_b32 %0, %1" : "+v"(a), "+v"(b));
}

// ---------------- pre-pass: K -> bf16, V -> bf16 transposed ----------------
__global__ __launch_bounds__(256, 4)
void prepass(const float* __restrict__ K, const float* __restrict__ V,
             short* __restrict__ Kbf, short* __restrict__ Vt)
{
    __shared__ short T[DH][LDSP];   // V^T tile

    const int tid  = threadIdx.x;
    const int wave = tid >> 6;
    const int lane = tid & 63;
    const int b  = blockIdx.x & 31;
    const int kt = blockIdx.x >> 5;
    const int k0 = kt * BK;
    const size_t bo = (size_t)b * SEQ * DH;

    // K tile convert: 4096 elems; thread: 2 chunks of 8 -> u32x4 stores
    const float* Ks = K + bo + (size_t)k0 * DH;
    u32* Kd = (u32*)(Kbf + bo + (size_t)k0 * DH);
    #pragma unroll
    for (int h = 0; h < 2; ++h) {
        const int c2 = tid + h * 256;          // 512 chunks of 8 elems
        f32x4 a = *(const f32x4*)(Ks + c2 * 8);
        f32x4 c = *(const f32x4*)(Ks + c2 * 8 + 4);
        u32x4 o;
        o[0] = pk2bf(a[0], a[1]); o[1] = pk2bf(a[2], a[3]);
        o[2] = pk2bf(c[0], c[1]); o[3] = pk2bf(c[2], c[3]);
        *(u32x4*)(Kd + c2 * 4) = o;
    }

    // V tile -> LDS transposed (one-time b16 scatter)
    #pragma unroll
    for (int h = 0; h < 2; ++h) {
        const int d0 = wave * 8 + h * 32;
        const float* src = V + bo + (size_t)(k0 + lane) * DH + d0;
        f32x4 va = *(const f32x4*)(src);
        f32x4 vb = *(const f32x4*)(src + 4);
        #pragma unroll
        for (int j = 0; j < 4; ++j) {
            T[d0 + j][lane]     = f2bf(va[j]);
            T[d0 + 4 + j][lane] = f2bf(vb[j]);
        }
    }
    __syncthreads();

    // write out Vt[b][d][k0+key], coalesced b128 rows
    short* Vd = Vt + (size_t)b * DH * SEQ;
    #pragma unroll
    for (int h = 0; h < 2; ++h) {
        const int c2 = tid + h * 256;          // 512 chunks: d = c2>>3, kc=(c2&7)*8
        const int d  = c2 >> 3;
        const int kc = (c2 & 7) * 8;
        *(bf16x8*)(Vd + (size_t)d * SEQ + k0 + kc) = *(const bf16x8*)(&T[d][kc]);
    }
}

// ---------------- main kernel ----------------
template <bool PRE>
__global__ __launch_bounds__(256, 2)
void attn_fwd(const float* __restrict__ Q,
              const float* __restrict__ Kf, const float* __restrict__ Vf,
              const short* __restrict__ Kbf, const short* __restrict__ Vtg,
              const int* __restrict__ VL, float* __restrict__ O)
{
    __shared__ __align__(16) short Klds[2][BK][LDSP];   // per-kg K tile [key][dim]
    __shared__ __align__(16) short Vt[2][DH][LDSP];     // per-kg V^T tile [dim][key]
    __shared__ int Rsort[32];

    const int tid  = threadIdx.x;
    const int wave = tid >> 6;
    const int lane = tid & 63;
    const int qg   = wave & 1;     // query half: q in [qg*32, qg*32+32)
    const int kg   = wave >> 1;    // key-tile parity this pair owns
    const int hi   = lane >> 5;
    const int l31  = lane & 31;
    const int pt   = (qg << 6) | lane;   // 0..127 within kg pair

    // LPT snake (R6): co-resident blocks get batch ranks {c,15-c,16+c,31-c}
    if (tid < 32) {
        const int nv = (VL[tid] + BK - 1) >> 6;
        int rank = 0;
        for (int jj = 0; jj < 32; ++jj) {
            const int nj = (VL[jj] + BK - 1) >> 6;
            rank += (nj > nv) || (nj == nv && jj < tid);
        }
        Rsort[rank] = tid;
    }
    __syncthreads();

    const int jb = blockIdx.x & 255;
    const int sl = blockIdx.x >> 8;
    const int c8 = jb >> 5;
    const int qt = jb & 31;
    const int rk = (sl == 0) ? c8 : (sl == 1) ? (15 - c8)
                 : (sl == 2) ? (16 + c8) : (31 - c8);
    const int b  = Rsort[rk];

    const int vl   = VL[b];
    const int nkt  = (vl + BK - 1) >> 6;
    const int nkt2 = (nkt + 1) >> 1;

    const size_t bo = (size_t)b * SEQ * DH;
    const short* Kb = Kbf + bo;                     // bf16 row-major (PRE)
    const short* Vb = Vtg + (size_t)b * DH * SEQ;   // bf16 [dim][key] (PRE)
    const float* Kb32 = Kf + bo;
    const float* Vb32 = Vf + bo;

    // Q B-frags, pre-scaled: p = exp2(S) = e^{qk/8}
    // B[k=16*st+8*hi+j][n=l31] = Q[qrow][16*st+8*hi+j]*SCLQ
    const int qrow = qt * 64 + qg * 32 + l31;
    bf16x8 aq[4];
    {
        const float* qp = Q + bo + (size_t)qrow * DH + hi * 8;
        #pragma unroll
        for (int st = 0; st < 4; ++st) {
            f32x4 a = *(const f32x4*)(qp + st * 16);
            f32x4 c = *(const f32x4*)(qp + st * 16 + 4);
            #pragma unroll
            for (int j = 0; j < 4; ++j) {
                aq[st][j]     = f2bf(a[j] * SCLQ);
                aq[st][j + 4] = f2bf(c[j] * SCLQ);
            }
        }
    }

    bf16x8 ones;
    #pragma unroll
    for (int j = 0; j < 8; ++j) ones[j] = (short)0x3F80;

    f32x16 oacc0, oacc1, lacc;
    #pragma unroll
    for (int i = 0; i < 16; ++i) { oacc0[i] = 0.f; oacc1[i] = 0.f; lacc[i] = 0.f; }

    // prologue prefetch: this pair's first tile kt=kg
    bf16x8 kpre[4], vpre[4];
    if (PRE && kg < nkt) {
        const size_t k0p = (size_t)kg * BK;
        #pragma unroll
        for (int h = 0; h < 4; ++h) {
            const int c = pt + h * 128;   // 512 chunks: row=c>>3, col=(c&7)*8
            kpre[h] = *(const bf16x8*)(Kb + k0p * DH + c * 8);
            vpre[h] = *(const bf16x8*)(Vb + (size_t)(c >> 3) * SEQ + k0p + (c & 7) * 8);
        }
    }

    int kt = kg;
    for (int it = 0; it < nkt2; ++it, kt += 2) {
        const bool act = (kt < nkt);
        const int k0 = kt * BK;

        // ---- stage this pair's tile -> LDS ----
        if (act) {
            if (PRE) {
                #pragma unroll
                for (int h = 0; h < 4; ++h) {
                    const int c = pt + h * 128;
                    *(bf16x8*)(&Klds[kg][c >> 3][(c & 7) * 8]) = kpre[h];
                    *(bf16x8*)(&Vt[kg][c >> 3][(c & 7) * 8])   = vpre[h];
                }
            } else {
                #pragma unroll
                for (int h = 0; h < 4; ++h) {
                    const int c = pt + h * 128;
                    const float* ks = Kb32 + (size_t)(k0 + (c >> 3)) * DH + (c & 7) * 8;
                    f32x4 a = *(const f32x4*)ks;
                    f32x4 d = *(const f32x4*)(ks + 4);
                    u32x4 o;
                    o[0] = pk2bf(a[0], a[1]); o[1] = pk2bf(a[2], a[3]);
                    o[2] = pk2bf(d[0], d[1]); o[3] = pk2bf(d[2], d[3]);
                    *(u32x4*)(&Klds[kg][c >> 3][(c & 7) * 8]) = o;
                }
                #pragma unroll
                for (int h = 0; h < 4; ++h) {
                    const int d0 = qg * 32 + h * 8;
                    const float* vs = Vb32 + (size_t)(k0 + lane) * DH + d0;
                    f32x4 a = *(const f32x4*)vs;
                    f32x4 d = *(const f32x4*)(vs + 4);
                    #pragma unroll
                    for (int j = 0; j < 4; ++j) {
                        Vt[kg][d0 + j][lane]     = f2bf(a[j]);
                        Vt[kg][d0 + 4 + j][lane] = f2bf(d[j]);
                    }
                }
            }
        }
        __syncthreads();

        // ---- prefetch this pair's next tile (kt+2) ----
        if (PRE && kt + 2 < nkt) {
            const size_t kn = (size_t)(k0 + 2 * BK);
            #pragma unroll
            for (int h = 0; h < 4; ++h) {
                const int c = pt + h * 128;
                kpre[h] = *(const bf16x8*)(Kb + kn * DH + c * 8);
                vpre[h] = *(const bf16x8*)(Vb + (size_t)(c >> 3) * SEQ + kn + (c & 7) * 8);
            }
        }

        if (act) {
            __builtin_amdgcn_s_setprio(1);
            // ---- S^T = K * Q^T : rows = keys, cols = q (l31) ----
            f32x16 s0, s1;
            #pragma unroll
            for (int i = 0; i < 16; ++i) { s0[i] = 0.f; s1[i] = 0.f; }
            #pragma unroll
            for (int st = 0; st < 4; ++st) {
                bf16x8 a0 = *(const bf16x8*)(&Klds[kg][l31][st * 16 + hi * 8]);
                bf16x8 a1 = *(const bf16x8*)(&Klds[kg][32 + l31][st * 16 + hi * 8]);
                s0 = __builtin_amdgcn_mfma_f32_32x32x16_bf16(a0, aq[st], s0, 0, 0, 0);
                s1 = __builtin_amdgcn_mfma_f32_32x32x16_bf16(a1, aq[st], s1, 0, 0, 0);
            }

            // ---- p = exp2(S); mask by key row on boundary tile only ----
            if (k0 + BK <= vl) {
                #pragma unroll
                for (int r = 0; r < 16; ++r) {
                    s0[r] = __builtin_amdgcn_exp2f(s0[r]);
                    s1[r] = __builtin_amdgcn_exp2f(s1[r]);
                }
            } else {
                #pragma unroll
                for (int r = 0; r < 16; ++r) {
                    const int krow = k0 + (r & 3) + 8 * (r >> 2) + 4 * hi;
                    s0[r] = (krow < vl)      ? __builtin_amdgcn_exp2f(s0[r]) : 0.f;
                    s1[r] = (krow + 32 < vl) ? __builtin_amdgcn_exp2f(s1[r]) : 0.f;
                }
            }

            // ---- pack to bf16 pairs: pk[w] = regs (2w, 2w+1) ----
            u32 pk0[8], pk1[8];
            #pragma unroll
            for (int i = 0; i < 8; ++i) {
                pk0[i] = pk2bf(s0[2 * i], s0[2 * i + 1]);
                pk1[i] = pk2bf(s1[2 * i], s1[2 * i + 1]);
            }

            // ---- in-register P exchange -> PV A-frags (no LDS) ----
            // dest(hi=0): w0,w1 = own pk[4t..4t+1]; w2,w3 = pk[4t..4t+1] from l+32
            // dest(hi=1): w0,w1 = pk[4t+2..4t+3] from l-32; w2,w3 = own pk[4t+2..]
            bf16x8 ap[4];
            #pragma unroll
            for (int t = 0; t < 2; ++t) {
                u32 x0 = pk0[4 * t], x1 = pk0[4 * t + 1];
                u32 x2 = pk0[4 * t + 2], x3 = pk0[4 * t + 3];
                pl32swap(x0, x2); pl32swap(x1, x3);
                u32x4 w; w[0] = x0; w[1] = x1; w[2] = x2; w[3] = x3;
                ap[t] = *(bf16x8*)&w;
                u32 y0 = pk1[4 * t], y1 = pk1[4 * t + 1];
                u32 y2 = pk1[4 * t + 2], y3 = pk1[4 * t + 3];
                pl32swap(y0, y2); pl32swap(y1, y3);
                u32x4 v; v[0] = y0; v[1] = y1; v[2] = y2; v[3] = y3;
                ap[2 + t] = *(bf16x8*)&v;
            }

            // ---- O += P V ; l += P * ones ----
            #pragma unroll
            for (int ks = 0; ks < 4; ++ks) {
                lacc = __builtin_amdgcn_mfma_f32_32x32x16_bf16(ap[ks], ones, lacc, 0, 0, 0);
                bf16x8 b0 = *(const bf16x8*)(&Vt[kg][l31][ks * 16 + hi * 8]);
                bf16x8 b1 = *(const bf16x8*)(&Vt[kg][32 + l31][ks * 16 + hi * 8]);
                oacc0 = __builtin_amdgcn_mfma_f32_32x32x16_bf16(ap[ks], b0, oacc0, 0, 0, 0);
                oacc1 = __builtin_amdgcn_mfma_f32_32x32x16_bf16(ap[ks], b1, oacc1, 0, 0, 0);
            }
            __builtin_amdgcn_s_setprio(0);
        }
        __syncthreads();
    }

    // ---- epilogue: combine kg partials, O = (oacc0+oacc1')/l ----
    // kg=1 waves dump partials to LDS (reuse tile buffers), kg=0 reduce+store.
    float* red = (qg ? (float*)&Vt[0][0][0] : (float*)&Klds[0][0][0]) + lane * 52;
    if (kg == 1) {
        *(f32x16*)(red)      = oacc0;
        *(f32x16*)(red + 16) = oacc1;
        *(f32x16*)(red + 32) = lacc;
    }
    __syncthreads();
    if (kg == 0) {
        f32x16 po0 = *(const f32x16*)(red);
        f32x16 po1 = *(const f32x16*)(red + 16);
        f32x16 pl  = *(const f32x16*)(red + 32);
        #pragma unroll
        for (int r = 0; r < 16; ++r) {
            const float inv = 1.0f / (lacc[r] + pl[r]);
            const int row = qt * 64 + qg * 32 + (r & 3) + 8 * (r >> 2) + 4 * hi;
            O[bo + (size_t)row * DH + l31]      = (oacc0[r] + po0[r]) * inv;
            O[bo + (size_t)row * DH + 32 + l31] = (oacc1[r] + po1[r]) * inv;
        }
    }
}

extern "C" void kernel_launch(void* const* d_in, const int* in_sizes, int n_in,
                              void* d_out, int out_size, void* d_ws, size_t ws_size,
                              hipStream_t stream) {
    const float* Q  = (const float*)d_in[0];
    const float* K  = (const float*)d_in[1];
    const float* V  = (const float*)d_in[2];
    const int*   VL = (const int*)d_in[3];
    float* O = (float*)d_out;

    const size_t nel = (size_t)32 * SEQ * DH;
    const size_t need = 2 * nel * sizeof(short);   // 16 MB (ws >= 68MB proven R5)
    if (ws_size >= need) {
        short* Kbf = (short*)d_ws;
        short* Vt  = Kbf + nel;
        prepass<<<dim3(1024), dim3(256), 0, stream>>>(K, V, Kbf, Vt);
        attn_fwd<true><<<dim3(1024), dim3(256), 0, stream>>>(Q, K, V, Kbf, Vt, VL, O);
    } else {
        attn_fwd<false><<<dim3(1024), dim3(256), 0, stream>>>(Q, K, V, nullptr, nullptr, VL, O);
    }
}